// Round 1
// baseline (3657.130 us; speedup 1.0000x reference)
//
#include <hip/hip_runtime.h>

#define HIDDEN 4096
#define INTER 14336
#define NTOK 8192   // B*S = 4*2048

typedef _Float16 half8 __attribute__((ext_vector_type(8)));
typedef float floatx4 __attribute__((ext_vector_type(4)));

#define AS1C(p) ((const __attribute__((address_space(1))) void*)(p))
#define AS3(p)  ((__attribute__((address_space(3))) void*)(p))

// ---------------- conversion kernels ----------------

__global__ void cvt_w_kernel(const int* __restrict__ src, _Float16* __restrict__ dst, long n) {
    long i0 = ((long)blockIdx.x * blockDim.x + threadIdx.x) * 8;
    long stride = (long)gridDim.x * blockDim.x * 8;
    for (long i = i0; i < n; i += stride) {
        int4 a = *(const int4*)(src + i);
        int4 b = *(const int4*)(src + i + 4);
        half8 h;
        h[0] = (_Float16)a.x; h[1] = (_Float16)a.y; h[2] = (_Float16)a.z; h[3] = (_Float16)a.w;
        h[4] = (_Float16)b.x; h[5] = (_Float16)b.y; h[6] = (_Float16)b.z; h[7] = (_Float16)b.w;
        *(half8*)(dst + i) = h;
    }
}

__global__ void cvt_x_kernel(const float* __restrict__ src, _Float16* __restrict__ dst, long n) {
    long i0 = ((long)blockIdx.x * blockDim.x + threadIdx.x) * 8;
    long stride = (long)gridDim.x * blockDim.x * 8;
    for (long i = i0; i < n; i += stride) {
        float4 a = *(const float4*)(src + i);
        float4 b = *(const float4*)(src + i + 4);
        half8 h;
        h[0] = (_Float16)a.x; h[1] = (_Float16)a.y; h[2] = (_Float16)a.z; h[3] = (_Float16)a.w;
        h[4] = (_Float16)b.x; h[5] = (_Float16)b.y; h[6] = (_Float16)b.z; h[7] = (_Float16)b.w;
        *(half8*)(dst + i) = h;
    }
}

// ---------------- fused gate+up GEMM + SwiGLU -> H (fp16) ----------------
// C[m,n] = sum_k X[m,k]*W[n,k]  (both K-major, "B^T" GEMM)
// tile 128x128, BK=32, 4 waves (2x2), each wave 64x64 = 4x4 frags of 16x16x32

__global__ __launch_bounds__(256, 2) void gateup_kernel(
        const _Float16* __restrict__ X,  const _Float16* __restrict__ Wg,
        const _Float16* __restrict__ Wu, const float* __restrict__ gs,
        const float* __restrict__ us,    _Float16* __restrict__ H)
{
    __shared__ _Float16 sA[128 * 32];
    __shared__ _Float16 sBg[128 * 32];
    __shared__ _Float16 sBu[128 * 32];

    const int tid  = threadIdx.x;
    const int lane = tid & 63;
    const int wid  = tid >> 6;
    const int wm   = wid >> 1;   // 0..1
    const int wn   = wid & 1;    // 0..1

    const int bm = blockIdx.x;   // M tiles fast: weight panel reused from L2
    const int bn = blockIdx.y;

    const long rowA0 = (long)bm * 128;
    const long rowB0 = (long)bn * 128;

    floatx4 accg[4][4] = {};
    floatx4 accu[4][4] = {};

    for (int kt = 0; kt < HIDDEN; kt += 32) {
        __syncthreads();
        #pragma unroll
        for (int it = 0; it < 2; ++it) {
            const int flat = it * 256 + tid;
            const int row  = flat >> 2;          // 64 B per row -> 4 threads/row
            const int c    = (flat & 3) * 8;     // fp16 elements
            __builtin_amdgcn_global_load_lds(AS1C(X  + (rowA0 + row) * HIDDEN + kt + c),
                                             AS3(sA  + flat * 8), 16, 0, 0);
            __builtin_amdgcn_global_load_lds(AS1C(Wg + (rowB0 + row) * HIDDEN + kt + c),
                                             AS3(sBg + flat * 8), 16, 0, 0);
            __builtin_amdgcn_global_load_lds(AS1C(Wu + (rowB0 + row) * HIDDEN + kt + c),
                                             AS3(sBu + flat * 8), 16, 0, 0);
        }
        __syncthreads();

        half8 a[4], bg[4], bu[4];
        const int kk = (lane >> 4) * 8;
        #pragma unroll
        for (int i = 0; i < 4; ++i) {
            const int r = wm * 64 + i * 16 + (lane & 15);
            a[i] = *(const half8*)(sA + r * 32 + kk);
        }
        #pragma unroll
        for (int j = 0; j < 4; ++j) {
            const int r = wn * 64 + j * 16 + (lane & 15);
            bg[j] = *(const half8*)(sBg + r * 32 + kk);
            bu[j] = *(const half8*)(sBu + r * 32 + kk);
        }
        #pragma unroll
        for (int i = 0; i < 4; ++i)
            #pragma unroll
            for (int j = 0; j < 4; ++j) {
                accg[i][j] = __builtin_amdgcn_mfma_f32_16x16x32_f16(a[i], bg[j], accg[i][j], 0, 0, 0);
                accu[i][j] = __builtin_amdgcn_mfma_f32_16x16x32_f16(a[i], bu[j], accu[i][j], 0, 0, 0);
            }
    }

    // epilogue: h = silu(g*gs) * (u*us), store fp16
    const int colBase = bn * 128 + wn * 64;
    const int rowBase = bm * 128 + wm * 64;
    #pragma unroll
    for (int j = 0; j < 4; ++j) {
        const int col = colBase + j * 16 + (lane & 15);
        const float gscale = gs[col];
        const float uscale = us[col];
        #pragma unroll
        for (int i = 0; i < 4; ++i) {
            const int row0 = rowBase + i * 16 + (lane >> 4) * 4;
            #pragma unroll
            for (int q = 0; q < 4; ++q) {
                const float g = accg[i][j][q] * gscale;
                const float u = accu[i][j][q] * uscale;
                const float h = g / (1.0f + __expf(-g)) * u;
                H[(long)(row0 + q) * INTER + col] = (_Float16)h;
            }
        }
    }
}

// ---------------- down GEMM -> out (fp32) ----------------

__global__ __launch_bounds__(256, 2) void down_kernel(
        const _Float16* __restrict__ Hm, const _Float16* __restrict__ Wd,
        const float* __restrict__ ds,    float* __restrict__ out)
{
    __shared__ _Float16 sA[128 * 32];
    __shared__ _Float16 sB[128 * 32];

    const int tid  = threadIdx.x;
    const int lane = tid & 63;
    const int wid  = tid >> 6;
    const int wm   = wid >> 1;
    const int wn   = wid & 1;

    const int bn = blockIdx.x;   // N tiles fast: H tile reused from L2, Wd LLC-resident
    const int bm = blockIdx.y;

    const long rowA0 = (long)bm * 128;
    const long rowB0 = (long)bn * 128;

    floatx4 acc[4][4] = {};

    for (int kt = 0; kt < INTER; kt += 32) {
        __syncthreads();
        #pragma unroll
        for (int it = 0; it < 2; ++it) {
            const int flat = it * 256 + tid;
            const int row  = flat >> 2;
            const int c    = (flat & 3) * 8;
            __builtin_amdgcn_global_load_lds(AS1C(Hm + (rowA0 + row) * INTER + kt + c),
                                             AS3(sA + flat * 8), 16, 0, 0);
            __builtin_amdgcn_global_load_lds(AS1C(Wd + (rowB0 + row) * INTER + kt + c),
                                             AS3(sB + flat * 8), 16, 0, 0);
        }
        __syncthreads();

        half8 a[4], b[4];
        const int kk = (lane >> 4) * 8;
        #pragma unroll
        for (int i = 0; i < 4; ++i) {
            const int r = wm * 64 + i * 16 + (lane & 15);
            a[i] = *(const half8*)(sA + r * 32 + kk);
        }
        #pragma unroll
        for (int j = 0; j < 4; ++j) {
            const int r = wn * 64 + j * 16 + (lane & 15);
            b[j] = *(const half8*)(sB + r * 32 + kk);
        }
        #pragma unroll
        for (int i = 0; i < 4; ++i)
            #pragma unroll
            for (int j = 0; j < 4; ++j)
                acc[i][j] = __builtin_amdgcn_mfma_f32_16x16x32_f16(a[i], b[j], acc[i][j], 0, 0, 0);
    }

    const int colBase = bn * 128 + wn * 64;
    const int rowBase = bm * 128 + wm * 64;
    #pragma unroll
    for (int j = 0; j < 4; ++j) {
        const int col = colBase + j * 16 + (lane & 15);
        const float dscale = ds[col];
        #pragma unroll
        for (int i = 0; i < 4; ++i) {
            const int row0 = rowBase + i * 16 + (lane >> 4) * 4;
            #pragma unroll
            for (int q = 0; q < 4; ++q)
                out[(long)(row0 + q) * HIDDEN + col] = acc[i][j][q] * dscale;
        }
    }
}

// ---------------- launch ----------------

extern "C" void kernel_launch(void* const* d_in, const int* in_sizes, int n_in,
                              void* d_out, int out_size, void* d_ws, size_t ws_size,
                              hipStream_t stream) {
    const float* x   = (const float*)d_in[0];
    const int*   gw  = (const int*)d_in[1];
    const float* gsc = (const float*)d_in[2];
    const int*   uw  = (const int*)d_in[3];
    const float* usc = (const float*)d_in[4];
    const int*   dw  = (const int*)d_in[5];
    const float* dsc = (const float*)d_in[6];
    float* out = (float*)d_out;

    char* ws = (char*)d_ws;
    _Float16* x16  = (_Float16*)(ws);                    //  64 MiB
    _Float16* wg16 = (_Float16*)(ws + 67108864ll);       // 112 MiB
    _Float16* wu16 = (_Float16*)(ws + 184549376ll);      // 112 MiB
    _Float16* wd16 = (_Float16*)(ws + 301989888ll);      // 112 MiB
    _Float16* h16  = (_Float16*)(ws + 419430400ll);      // 224 MiB

    cvt_x_kernel<<<4096, 256, 0, stream>>>(x,  x16,  (long)NTOK * HIDDEN);
    cvt_w_kernel<<<4096, 256, 0, stream>>>(gw, wg16, (long)INTER * HIDDEN);
    cvt_w_kernel<<<4096, 256, 0, stream>>>(uw, wu16, (long)INTER * HIDDEN);
    cvt_w_kernel<<<4096, 256, 0, stream>>>(dw, wd16, (long)HIDDEN * INTER);

    gateup_kernel<<<dim3(NTOK / 128, INTER / 128), 256, 0, stream>>>(x16, wg16, wu16, gsc, usc, h16);
    down_kernel<<<dim3(HIDDEN / 128, NTOK / 128), 256, 0, stream>>>(h16, wd16, dsc, out);
}

// Round 2
// 3411.253 us; speedup vs baseline: 1.0721x; 1.0721x over previous
//
#include <hip/hip_runtime.h>

#define HIDDEN 4096
#define INTER 14336
#define NTOK 8192   // B*S = 4*2048

typedef _Float16 half8 __attribute__((ext_vector_type(8)));
typedef float floatx4 __attribute__((ext_vector_type(4)));

#define AS1C(p) ((const __attribute__((address_space(1))) void*)(p))
#define AS3(p)  ((__attribute__((address_space(3))) void*)(p))
#define BAR()   asm volatile("s_barrier" ::: "memory")

// ---------------- conversion kernels ----------------

__global__ void cvt_w_kernel(const int* __restrict__ src, _Float16* __restrict__ dst, long n) {
    long i0 = ((long)blockIdx.x * blockDim.x + threadIdx.x) * 8;
    long stride = (long)gridDim.x * blockDim.x * 8;
    for (long i = i0; i < n; i += stride) {
        int4 a = *(const int4*)(src + i);
        int4 b = *(const int4*)(src + i + 4);
        half8 h;
        h[0] = (_Float16)a.x; h[1] = (_Float16)a.y; h[2] = (_Float16)a.z; h[3] = (_Float16)a.w;
        h[4] = (_Float16)b.x; h[5] = (_Float16)b.y; h[6] = (_Float16)b.z; h[7] = (_Float16)b.w;
        *(half8*)(dst + i) = h;
    }
}

__global__ void cvt_x_kernel(const float* __restrict__ src, _Float16* __restrict__ dst, long n) {
    long i0 = ((long)blockIdx.x * blockDim.x + threadIdx.x) * 8;
    long stride = (long)gridDim.x * blockDim.x * 8;
    for (long i = i0; i < n; i += stride) {
        float4 a = *(const float4*)(src + i);
        float4 b = *(const float4*)(src + i + 4);
        half8 h;
        h[0] = (_Float16)a.x; h[1] = (_Float16)a.y; h[2] = (_Float16)a.z; h[3] = (_Float16)a.w;
        h[4] = (_Float16)b.x; h[5] = (_Float16)b.y; h[6] = (_Float16)b.z; h[7] = (_Float16)b.w;
        *(half8*)(dst + i) = h;
    }
}

// ---------------- 8-phase 256x256 GEMM template ----------------
// C[m,n] = sum_k A[m,k]*B[n,k], both K-major. BM=BN=256, BK=64, 512 thr (8 waves 2x4).
// Per-wave output 128x64 = 8x4 frags of 16x16. LDS 128KB: 2dbuf x (A 32KB + B 32KB).
// T2 swizzle: 16B slot ^= (row&7), applied on global SRC (staging) + ds_read addr.
// MODE 0: gate -> write fp16 g*scale. MODE 1: up -> h=silu(g)*u in-place over gbuf.
// MODE 2: down -> write fp32 acc*scale.

__device__ __forceinline__ void stage_half(const _Float16* __restrict__ src, long row0,
                                           int ldk, int kt, _Float16* lds, int half, int tid) {
#pragma unroll
    for (int pp = 0; pp < 2; ++pp) {
        const int p = half * 2 + pp;
        const int r = tid >> 3;                 // 0..63 rows per pass
        const int row = p * 64 + r;
        const int slot = (tid & 7) ^ (r & 7);   // pre-swizzled global source slot
        __builtin_amdgcn_global_load_lds(AS1C(src + (row0 + row) * (long)ldk + kt + slot * 8),
                                         AS3(lds + p * 4096 + tid * 8), 16, 0, 0);
    }
}

__device__ __forceinline__ half8 ldsfrag(const _Float16* buf, int row, int khalf, int lane) {
    const int slot = ((khalf * 4 + (lane >> 4)) ^ (row & 7));
    return *(const half8*)(buf + row * 64 + slot * 8);
}

template<int KDIM, int NBN, int MODE>
__global__ __launch_bounds__(512, 2) void gemm8p(
        const _Float16* __restrict__ Aptr, const _Float16* __restrict__ Bptr,
        const float* __restrict__ scale, _Float16* __restrict__ gbuf, void* __restrict__ outp)
{
    constexpr int NT = KDIM / 64;
    __shared__ _Float16 sA[2][256 * 64];
    __shared__ _Float16 sB[2][256 * 64];

    const int tid  = threadIdx.x;
    const int lane = tid & 63;
    const int wid  = tid >> 6;
    const int wr   = wid >> 2;   // 0..1
    const int wc   = wid & 3;    // 0..3

    // T1: bijective XCD swizzle (grid % 8 == 0 for all our launches)
    const int nwg = gridDim.x;
    const int bid = blockIdx.x;
    const int swz = (bid & 7) * (nwg >> 3) + (bid >> 3);
    const int bm = swz / NBN;
    const int bn = swz % NBN;
    const long rowA0 = (long)bm * 256;
    const long rowB0 = (long)bn * 256;

    floatx4 acc[8][4] = {};
    half8 a[4][2], b0[2][2], b1[2][2];

    const int mrow = wr * 128 + (lane & 15);   // A-tile row base (+m*16)
    const int ncol = wc * 64  + (lane & 15);   // B-tile row base (+n*16)

    // ---- prologue: tile0 fully (8 loads) + tile1 Bh0,Bh1,Ah0 (6 loads) ----
    stage_half(Bptr, rowB0, KDIM, 0,  &sB[0][0], 0, tid);
    stage_half(Bptr, rowB0, KDIM, 0,  &sB[0][0], 1, tid);
    stage_half(Aptr, rowA0, KDIM, 0,  &sA[0][0], 0, tid);
    stage_half(Aptr, rowA0, KDIM, 0,  &sA[0][0], 1, tid);
    stage_half(Bptr, rowB0, KDIM, 64, &sB[1][0], 0, tid);
    stage_half(Bptr, rowB0, KDIM, 64, &sB[1][0], 1, tid);
    stage_half(Aptr, rowA0, KDIM, 64, &sA[1][0], 0, tid);
    asm volatile("s_waitcnt vmcnt(6)" ::: "memory");
    BAR();

    for (int t = 0; t < NT; ++t) {
        const _Float16* Ac = &sA[t & 1][0];
        const _Float16* Bc = &sB[t & 1][0];
        _Float16* An = &sA[(t + 1) & 1][0];
        _Float16* Aw = &sA[t & 1][0];   // t+2 lands in cur buffer
        _Float16* Bw = &sB[t & 1][0];
        const int kt1 = (t + 1) * 64;
        const int kt2 = (t + 2) * 64;
        const bool p1 = (t + 1 < NT);
        const bool p2 = (t + 2 < NT);

        // ---- P0: ds A[m0-3]k* (8) + B[n0-1]k* (4); issue (t+1) Ah1 ----
#pragma unroll
        for (int m = 0; m < 4; ++m) {
            a[m][0] = ldsfrag(Ac, mrow + m * 16, 0, lane);
            a[m][1] = ldsfrag(Ac, mrow + m * 16, 1, lane);
        }
#pragma unroll
        for (int n = 0; n < 2; ++n) {
            b0[n][0] = ldsfrag(Bc, ncol + n * 16, 0, lane);
            b0[n][1] = ldsfrag(Bc, ncol + n * 16, 1, lane);
        }
        if (p1) stage_half(Aptr, rowA0, KDIM, kt1, An, 1, tid);
        BAR();
        __builtin_amdgcn_s_setprio(1);
#pragma unroll
        for (int m = 0; m < 4; ++m)
#pragma unroll
            for (int n = 0; n < 2; ++n) {
                acc[m][n] = __builtin_amdgcn_mfma_f32_16x16x32_f16(a[m][0], b0[n][0], acc[m][n], 0, 0, 0);
                acc[m][n] = __builtin_amdgcn_mfma_f32_16x16x32_f16(a[m][1], b0[n][1], acc[m][n], 0, 0, 0);
            }
        __builtin_amdgcn_s_setprio(0);
        BAR();

        // ---- P1: ds B[n2-3]k* (4); no issue (B regions still being consumed) ----
#pragma unroll
        for (int n = 0; n < 2; ++n) {
            b1[n][0] = ldsfrag(Bc, ncol + (2 + n) * 16, 0, lane);
            b1[n][1] = ldsfrag(Bc, ncol + (2 + n) * 16, 1, lane);
        }
        BAR();
        __builtin_amdgcn_s_setprio(1);
#pragma unroll
        for (int m = 0; m < 4; ++m)
#pragma unroll
            for (int n = 0; n < 2; ++n) {
                acc[m][2 + n] = __builtin_amdgcn_mfma_f32_16x16x32_f16(a[m][0], b1[n][0], acc[m][2 + n], 0, 0, 0);
                acc[m][2 + n] = __builtin_amdgcn_mfma_f32_16x16x32_f16(a[m][1], b1[n][1], acc[m][2 + n], 0, 0, 0);
            }
        __builtin_amdgcn_s_setprio(0);
        BAR();

        // ---- P2: ds A[m4-7]k* (8); issue (t+2) Bh0 (B fully consumed by P1) ----
#pragma unroll
        for (int m = 0; m < 4; ++m) {
            a[m][0] = ldsfrag(Ac, mrow + (4 + m) * 16, 0, lane);
            a[m][1] = ldsfrag(Ac, mrow + (4 + m) * 16, 1, lane);
        }
        if (p2) stage_half(Bptr, rowB0, KDIM, kt2, Bw, 0, tid);
        BAR();
        __builtin_amdgcn_s_setprio(1);
#pragma unroll
        for (int m = 0; m < 4; ++m)
#pragma unroll
            for (int n = 0; n < 2; ++n) {
                acc[4 + m][2 + n] = __builtin_amdgcn_mfma_f32_16x16x32_f16(a[m][0], b1[n][0], acc[4 + m][2 + n], 0, 0, 0);
                acc[4 + m][2 + n] = __builtin_amdgcn_mfma_f32_16x16x32_f16(a[m][1], b1[n][1], acc[4 + m][2 + n], 0, 0, 0);
            }
        __builtin_amdgcn_s_setprio(0);
        BAR();

        // ---- P3: no ds; issue (t+2) Bh1 + Ah0 (A fully consumed by P2); tile wait ----
        if (p2) {
            stage_half(Bptr, rowB0, KDIM, kt2, Bw, 1, tid);
            stage_half(Aptr, rowA0, KDIM, kt2, Aw, 0, tid);
        }
        BAR();
        __builtin_amdgcn_s_setprio(1);
#pragma unroll
        for (int m = 0; m < 4; ++m)
#pragma unroll
            for (int n = 0; n < 2; ++n) {
                acc[4 + m][n] = __builtin_amdgcn_mfma_f32_16x16x32_f16(a[m][0], b0[n][0], acc[4 + m][n], 0, 0, 0);
                acc[4 + m][n] = __builtin_amdgcn_mfma_f32_16x16x32_f16(a[m][1], b0[n][1], acc[4 + m][n], 0, 0, 0);
            }
        __builtin_amdgcn_s_setprio(0);
        if (p2) { asm volatile("s_waitcnt vmcnt(6)" ::: "memory"); }
        else    { asm volatile("s_waitcnt vmcnt(0)" ::: "memory"); }
        BAR();
    }

    // ---- epilogue ----
    const int orow = bm * 256 + wr * 128 + ((lane >> 4) * 4);
    const int ocol = bn * 256 + wc * 64 + (lane & 15);
#pragma unroll
    for (int n = 0; n < 4; ++n) {
        const int col = ocol + n * 16;
        const float sc = scale[col];
#pragma unroll
        for (int m = 0; m < 8; ++m) {
            const int row = orow + m * 16;
#pragma unroll
            for (int q = 0; q < 4; ++q) {
                if (MODE == 0) {
                    _Float16* G = (_Float16*)outp;
                    G[(long)(row + q) * INTER + col] = (_Float16)(acc[m][n][q] * sc);
                } else if (MODE == 1) {
                    _Float16* H = (_Float16*)outp;   // == gbuf, in-place
                    const long idx = (long)(row + q) * INTER + col;
                    const float g = (float)gbuf[idx];
                    const float u = acc[m][n][q] * sc;
                    H[idx] = (_Float16)(g / (1.0f + __expf(-g)) * u);
                } else {
                    float* O = (float*)outp;
                    O[(long)(row + q) * HIDDEN + col] = acc[m][n][q] * sc;
                }
            }
        }
    }
}

// ---------------- launch ----------------

extern "C" void kernel_launch(void* const* d_in, const int* in_sizes, int n_in,
                              void* d_out, int out_size, void* d_ws, size_t ws_size,
                              hipStream_t stream) {
    const float* x   = (const float*)d_in[0];
    const int*   gw  = (const int*)d_in[1];
    const float* gsc = (const float*)d_in[2];
    const int*   uw  = (const int*)d_in[3];
    const float* usc = (const float*)d_in[4];
    const int*   dw  = (const int*)d_in[5];
    const float* dsc = (const float*)d_in[6];
    float* out = (float*)d_out;

    char* ws = (char*)d_ws;
    _Float16* x16  = (_Float16*)(ws);                    //  64 MiB
    _Float16* wg16 = (_Float16*)(ws + 67108864ll);       // 112 MiB
    _Float16* wu16 = (_Float16*)(ws + 184549376ll);      // 112 MiB
    _Float16* wd16 = (_Float16*)(ws + 301989888ll);      // 112 MiB
    _Float16* gh16 = (_Float16*)(ws + 419430400ll);      // 224 MiB (g, then h in-place)

    cvt_x_kernel<<<4096, 256, 0, stream>>>(x,  x16,  (long)NTOK * HIDDEN);
    cvt_w_kernel<<<4096, 256, 0, stream>>>(gw, wg16, (long)INTER * HIDDEN);
    cvt_w_kernel<<<4096, 256, 0, stream>>>(uw, wu16, (long)INTER * HIDDEN);
    cvt_w_kernel<<<4096, 256, 0, stream>>>(dw, wd16, (long)HIDDEN * INTER);

    // gate: [8192 x 14336] = X * Wg^T, write g16
    gemm8p<HIDDEN, 56, 0><<<(NTOK / 256) * (INTER / 256), 512, 0, stream>>>(
        x16, wg16, gsc, nullptr, gh16);
    // up: same shape, epilogue h = silu(g) * u, in-place over gh16
    gemm8p<HIDDEN, 56, 1><<<(NTOK / 256) * (INTER / 256), 512, 0, stream>>>(
        x16, wu16, usc, gh16, gh16);
    // down: [8192 x 4096] = H * Wd^T, fp32 out
    gemm8p<INTER, 16, 2><<<(NTOK / 256) * (HIDDEN / 256), 512, 0, stream>>>(
        gh16, wd16, dsc, nullptr, out);
}